// Round 2
// baseline (355.803 us; speedup 1.0000x reference)
//
#include <hip/hip_runtime.h>
#include <hip/hip_bf16.h>
#include <math.h>

#define N 1024
#define K 48
#define A 5
#define LOCALD 512
#define PAIRD 128
#define KT 8

// ws layout (floats): R[N*9], t[N*3], xs[N*15], li[N*128], lj[N*128]
#define WS_R  0
#define WS_T  (WS_R + N*9)
#define WS_XS (WS_T + N*3)
#define WS_LI (WS_XS + N*15)
#define WS_LJ (WS_LI + N*128)

__device__ __forceinline__ float gelu_tanh(float x) {
    float x3 = x * x * x;
    float u = 0.7978845608028654f * (x + 0.044715f * x3);
    return 0.5f * x * (1.0f + tanhf(u));
}

__global__ __launch_bounds__(256) void prep_kernel(
    const float* __restrict__ local_, const float* __restrict__ pos,
    const float* __restrict__ W_li, const float* __restrict__ W_lj,
    float* __restrict__ ws)
{
    const int n0 = blockIdx.x * 8;
    const int tid = threadIdx.x;
    __shared__ float sl[8][LOCALD];
    __shared__ float sR8[8][9];
    __shared__ float st8[8][3];

    for (int t = tid; t < 8 * LOCALD; t += 256) {
        int r = t >> 9, q = t & 511;
        sl[r][q] = local_[(size_t)(n0 + r) * LOCALD + q];
    }
    if (tid < 8) {
        int n = n0 + tid;
        const float* pp = pos + (size_t)n * 15;
        float nx = pp[0], ny = pp[1], nz = pp[2];
        float cax = pp[3], cay = pp[4], caz = pp[5];
        float cx = pp[6], cy = pp[7], cz = pp[8];
        float e1x = cx - cax, e1y = cy - cay, e1z = cz - caz;
        float inv1 = rsqrtf(e1x * e1x + e1y * e1y + e1z * e1z + 1e-8f);
        e1x *= inv1; e1y *= inv1; e1z *= inv1;
        float v2x = nx - cax, v2y = ny - cay, v2z = nz - caz;
        float dp = v2x * e1x + v2y * e1y + v2z * e1z;
        float e2x = v2x - dp * e1x, e2y = v2y - dp * e1y, e2z = v2z - dp * e1z;
        float inv2 = rsqrtf(e2x * e2x + e2y * e2y + e2z * e2z + 1e-8f);
        e2x *= inv2; e2y *= inv2; e2z *= inv2;
        float e3x = e1y * e2z - e1z * e2y;
        float e3y = e1z * e2x - e1x * e2z;
        float e3z = e1x * e2y - e1y * e2x;
        // R[i][col]: col0=e1, col1=e2, col2=e3 ; stored row-major i*3+col
        sR8[tid][0] = e1x; sR8[tid][1] = e2x; sR8[tid][2] = e3x;
        sR8[tid][3] = e1y; sR8[tid][4] = e2y; sR8[tid][5] = e3y;
        sR8[tid][6] = e1z; sR8[tid][7] = e2z; sR8[tid][8] = e3z;
        st8[tid][0] = cax; st8[tid][1] = cay; st8[tid][2] = caz;
        #pragma unroll
        for (int i = 0; i < 9; ++i) ws[WS_R + (size_t)n * 9 + i] = sR8[tid][i];
        #pragma unroll
        for (int i = 0; i < 3; ++i) ws[WS_T + (size_t)n * 3 + i] = st8[tid][i];
    }
    __syncthreads();

    // x_self[a][d] = sum_i R[i*3+d] * (pos[a][i] - t[i])
    for (int t = tid; t < 8 * 15; t += 256) {
        int r = t / 15, q = t % 15, a = q / 3, dd = q % 3;
        int n = n0 + r;
        const float* pp = pos + (size_t)n * 15 + a * 3;
        float v = sR8[r][0 * 3 + dd] * (pp[0] - st8[r][0])
                + sR8[r][1 * 3 + dd] * (pp[1] - st8[r][1])
                + sR8[r][2 * 3 + dd] * (pp[2] - st8[r][2]);
        ws[WS_XS + (size_t)n * 15 + q] = v;
    }

    // li/lj: each half-block (128 ch) accumulates 4 rows
    const int c = tid & 127;
    const int hh = tid >> 7;
    const int r0 = hh * 4;
    float ali0 = 0, ali1 = 0, ali2 = 0, ali3 = 0;
    float alj0 = 0, alj1 = 0, alj2 = 0, alj3 = 0;
    const float* wli = W_li + c;
    const float* wlj = W_lj + c;
    __syncthreads();
    for (int f = 0; f < LOCALD; ++f) {
        float a_ = wli[(size_t)f * 128];
        float b_ = wlj[(size_t)f * 128];
        float l0 = sl[r0 + 0][f], l1 = sl[r0 + 1][f], l2 = sl[r0 + 2][f], l3 = sl[r0 + 3][f];
        ali0 += l0 * a_; ali1 += l1 * a_; ali2 += l2 * a_; ali3 += l3 * a_;
        alj0 += l0 * b_; alj1 += l1 * b_; alj2 += l2 * b_; alj3 += l3 * b_;
    }
    ws[WS_LI + (size_t)(n0 + r0 + 0) * 128 + c] = ali0;
    ws[WS_LI + (size_t)(n0 + r0 + 1) * 128 + c] = ali1;
    ws[WS_LI + (size_t)(n0 + r0 + 2) * 128 + c] = ali2;
    ws[WS_LI + (size_t)(n0 + r0 + 3) * 128 + c] = ali3;
    ws[WS_LJ + (size_t)(n0 + r0 + 0) * 128 + c] = alj0;
    ws[WS_LJ + (size_t)(n0 + r0 + 1) * 128 + c] = alj1;
    ws[WS_LJ + (size_t)(n0 + r0 + 2) * 128 + c] = alj2;
    ws[WS_LJ + (size_t)(n0 + r0 + 3) * 128 + c] = alj3;
}

__global__ __launch_bounds__(256) void main_kernel(
    const float* __restrict__ pair, const float* __restrict__ pos,
    const int* __restrict__ neigh, const int* __restrict__ mask,
    const float* __restrict__ W_dist, const float* __restrict__ W_dir,
    const float* __restrict__ W_rot, const float* __restrict__ W_vec,
    const float* __restrict__ ln_s, const float* __restrict__ ln_b,
    const float* __restrict__ w1, const float* __restrict__ b1,
    const float* __restrict__ w2, const float* __restrict__ b2,
    const float* __restrict__ ws, float* __restrict__ out)
{
    const int nblk = blockIdx.x / (K / KT);
    const int k0 = (blockIdx.x % (K / KT)) * KT;
    const int tid = threadIdx.x;

    __shared__ int s_nb[KT];
    __shared__ float spn[15], sR[9], st[3], sxs[15], sli[128];
    __shared__ float spj[KT][16];
    __shared__ float sRj[KT][12];
    __shared__ float feat[KT][516];   // [0,400) rbf, [400,475) dir, [475,484) rrel, [484,514) vec
    __shared__ float pbuf[KT][128];
    __shared__ float hbuf[KT][256];

    const float* Rws = ws + WS_R;
    const float* xws = ws + WS_XS;
    const float* liws = ws + WS_LI;
    const float* ljws = ws + WS_LJ;

    if (tid < KT) s_nb[tid] = neigh[(size_t)nblk * K + k0 + tid];
    if (tid >= 32 && tid < 32 + 15) spn[tid - 32] = pos[(size_t)nblk * 15 + (tid - 32)];
    if (tid >= 64 && tid < 64 + 9)  sR[tid - 64] = Rws[(size_t)nblk * 9 + (tid - 64)];
    if (tid >= 96 && tid < 96 + 3)  st[tid - 96] = ws[WS_T + (size_t)nblk * 3 + (tid - 96)];
    if (tid >= 104 && tid < 104 + 15) sxs[tid - 104] = xws[(size_t)nblk * 15 + (tid - 104)];
    if (tid >= 128) sli[tid - 128] = liws[(size_t)nblk * 128 + (tid - 128)];
    __syncthreads();

    for (int t = tid; t < KT * 15; t += 256) {
        int r = t / 15, q = t % 15;
        int j = s_nb[r]; if (j < 0) j += N;
        spj[r][q] = pos[(size_t)j * 15 + q];
    }
    for (int t = tid; t < KT * 9; t += 256) {
        int r = t / 9, q = t % 9;
        int j = s_nb[r]; if (j < 0) j += N;
        sRj[r][q] = Rws[(size_t)j * 9 + q];
    }
    __syncthreads();

    // geometry: rbf (16 bins) + normalized off_local (3) per (a,b)
    for (int t = tid; t < KT * 25; t += 256) {
        int r = t / 25, ab = t % 25, a = ab / 5, b = ab % 5;
        float o0 = spn[a * 3 + 0] - spj[r][b * 3 + 0];
        float o1 = spn[a * 3 + 1] - spj[r][b * 3 + 1];
        float o2 = spn[a * 3 + 2] - spj[r][b * 3 + 2];
        float d = sqrtf(o0 * o0 + o1 * o1 + o2 * o2 + 1e-8f);
        const float inv_step = 16.0f / 22.0f;
        int base = a * 80 + b * 16;
        #pragma unroll
        for (int bin = 0; bin < 16; ++bin) {
            float cen = (22.0f / 15.0f) * bin;
            float z = (d - cen) * inv_step;
            feat[r][base + bin] = __expf(-z * z);
        }
        float l0 = sR[0] * o0 + sR[3] * o1 + sR[6] * o2;
        float l1 = sR[1] * o0 + sR[4] * o1 + sR[7] * o2;
        float l2 = sR[2] * o0 + sR[5] * o1 + sR[8] * o2;
        float inv = rsqrtf(l0 * l0 + l1 * l1 + l2 * l2 + 1e-8f);
        int dbase = 400 + a * 15 + b * 3;
        feat[r][dbase + 0] = l0 * inv;
        feat[r][dbase + 1] = l1 * inv;
        feat[r][dbase + 2] = l2 * inv;
    }
    // R_rel[i][jd] = sum_a R_n[a*3+i] * R_j[a*3+jd]
    for (int t = tid; t < KT * 9; t += 256) {
        int r = t / 9, q = t % 9, i = q / 3, jd = q % 3;
        float v = sR[0 * 3 + i] * sRj[r][0 * 3 + jd]
                + sR[1 * 3 + i] * sRj[r][1 * 3 + jd]
                + sR[2 * 3 + i] * sRj[r][2 * 3 + jd];
        feat[r][475 + q] = v;
    }
    // vec: [a*6+d] = 0.1*x_self, [a*6+3+d] = 0.1*x_nb
    for (int t = tid; t < KT * 15; t += 256) {
        int r = t / 15, q = t % 15, a = q / 3, dd = q % 3;
        float xn = sR[0 * 3 + dd] * (spj[r][a * 3 + 0] - st[0])
                 + sR[1 * 3 + dd] * (spj[r][a * 3 + 1] - st[1])
                 + sR[2 * 3 + dd] * (spj[r][a * 3 + 2] - st[2]);
        feat[r][484 + a * 6 + dd] = 0.1f * sxs[q];
        feat[r][484 + a * 6 + 3 + dd] = 0.1f * xn;
    }
    __syncthreads();

    // feature matvec: each half-block does 4 rows x 128 channels
    const int c = tid & 127;
    const int hh = tid >> 7;
    const int r0 = hh * 4;
    float a0 = 0, a1 = 0, a2 = 0, a3 = 0;
    {
        const float* w = W_dist + c;
        for (int f = 0; f < 400; ++f) {
            float wv = w[(size_t)f * 128];
            a0 += feat[r0 + 0][f] * wv; a1 += feat[r0 + 1][f] * wv;
            a2 += feat[r0 + 2][f] * wv; a3 += feat[r0 + 3][f] * wv;
        }
        w = W_dir + c;
        for (int f = 0; f < 75; ++f) {
            float wv = w[(size_t)f * 128];
            a0 += feat[r0 + 0][400 + f] * wv; a1 += feat[r0 + 1][400 + f] * wv;
            a2 += feat[r0 + 2][400 + f] * wv; a3 += feat[r0 + 3][400 + f] * wv;
        }
        w = W_rot + c;
        for (int f = 0; f < 9; ++f) {
            float wv = w[(size_t)f * 128];
            a0 += feat[r0 + 0][475 + f] * wv; a1 += feat[r0 + 1][475 + f] * wv;
            a2 += feat[r0 + 2][475 + f] * wv; a3 += feat[r0 + 3][475 + f] * wv;
        }
        w = W_vec + c;
        for (int f = 0; f < 30; ++f) {
            float wv = w[(size_t)f * 128];
            a0 += feat[r0 + 0][484 + f] * wv; a1 += feat[r0 + 1][484 + f] * wv;
            a2 += feat[r0 + 2][484 + f] * wv; a3 += feat[r0 + 3][484 + f] * wv;
        }
    }
    {
        float accs[4] = {a0, a1, a2, a3};
        #pragma unroll
        for (int i = 0; i < 4; ++i) {
            int kk = r0 + i;
            int j = s_nb[kk]; if (j < 0) j += N;
            float v = accs[i]
                    + pair[((size_t)nblk * N + j) * PAIRD + c]
                    + sli[c] + ljws[(size_t)j * 128 + c];
            pbuf[kk][c] = v;
        }
    }
    __syncthreads();

    // LayerNorm: wave w handles rows 2w, 2w+1
    {
        int wave = tid >> 6, lane = tid & 63;
        #pragma unroll
        for (int rr = 0; rr < 2; ++rr) {
            int row = wave * 2 + rr;
            float v0 = pbuf[row][lane], v1 = pbuf[row][lane + 64];
            float s = v0 + v1, s2 = v0 * v0 + v1 * v1;
            #pragma unroll
            for (int o = 32; o > 0; o >>= 1) {
                s += __shfl_xor(s, o, 64);
                s2 += __shfl_xor(s2, o, 64);
            }
            float mu = s * (1.0f / 128.0f);
            float var = s2 * (1.0f / 128.0f) - mu * mu;
            float rs = rsqrtf(var + 1e-5f);
            pbuf[row][lane]      = (v0 - mu) * rs * ln_s[lane] + ln_b[lane];
            pbuf[row][lane + 64] = (v1 - mu) * rs * ln_s[lane + 64] + ln_b[lane + 64];
        }
    }
    __syncthreads();

    // MLP layer 1: h[row][tid] over 8 rows
    {
        float ha[8] = {0, 0, 0, 0, 0, 0, 0, 0};
        const float* w = w1 + tid;
        for (int f = 0; f < 128; ++f) {
            float wv = w[(size_t)f * 256];
            #pragma unroll
            for (int r = 0; r < 8; ++r) ha[r] += pbuf[r][f] * wv;
        }
        float bb = b1[tid];
        #pragma unroll
        for (int r = 0; r < 8; ++r) hbuf[r][tid] = gelu_tanh(ha[r] + bb);
    }
    __syncthreads();

    // MLP layer 2 + output
    {
        float oa0 = 0, oa1 = 0, oa2 = 0, oa3 = 0;
        const float* w = w2 + c;
        for (int f = 0; f < 256; ++f) {
            float wv = w[(size_t)f * 128];
            oa0 += hbuf[r0 + 0][f] * wv; oa1 += hbuf[r0 + 1][f] * wv;
            oa2 += hbuf[r0 + 2][f] * wv; oa3 += hbuf[r0 + 3][f] * wv;
        }
        float bb2 = b2[c];
        float oas[4] = {oa0, oa1, oa2, oa3};
        #pragma unroll
        for (int i = 0; i < 4; ++i) {
            int kk = r0 + i;
            out[((size_t)nblk * K + (k0 + kk)) * PAIRD + c] = oas[i] + bb2;
        }
    }
    // pair_mask
    if (tid < KT) {
        int j = s_nb[tid];
        int jj = j < 0 ? j + N : j;
        bool pm = (j != -1) && (mask[nblk] != 0) && (mask[jj] != 0);
        out[(size_t)N * K * PAIRD + (size_t)nblk * K + k0 + tid] = pm ? 1.0f : 0.0f;
    }
}

extern "C" void kernel_launch(void* const* d_in, const int* in_sizes, int n_in,
                              void* d_out, int out_size, void* d_ws, size_t ws_size,
                              hipStream_t stream) {
    const float* local_ = (const float*)d_in[0];
    const float* pos = (const float*)d_in[1];
    const float* pair = (const float*)d_in[2];
    const int* neigh = (const int*)d_in[3];
    const int* mask = (const int*)d_in[4];
    const float* W_li = (const float*)d_in[5];
    const float* W_lj = (const float*)d_in[6];
    const float* W_dist = (const float*)d_in[7];
    const float* W_dir = (const float*)d_in[8];
    const float* W_rot = (const float*)d_in[9];
    const float* W_vec = (const float*)d_in[10];
    const float* ln_s = (const float*)d_in[11];
    const float* ln_b = (const float*)d_in[12];
    const float* w1 = (const float*)d_in[13];
    const float* b1 = (const float*)d_in[14];
    const float* w2 = (const float*)d_in[15];
    const float* b2 = (const float*)d_in[16];
    float* ws = (float*)d_ws;
    float* out = (float*)d_out;

    hipLaunchKernelGGL(prep_kernel, dim3(N / 8), dim3(256), 0, stream,
                       local_, pos, W_li, W_lj, ws);
    hipLaunchKernelGGL(main_kernel, dim3(N * (K / KT)), dim3(256), 0, stream,
                       pair, pos, neigh, mask, W_dist, W_dir, W_rot, W_vec,
                       ln_s, ln_b, w1, b1, w2, b2, ws, out);
}

// Round 3
// 123.353 us; speedup vs baseline: 2.8844x; 2.8844x over previous
//
#include <hip/hip_runtime.h>
#include <hip/hip_bf16.h>
#include <math.h>

#define N 1024
#define K 48
#define A 5
#define LOCALD 512
#define PAIRD 128
#define ROWS 32
#define FEATK 544            // 34 * 16, zero-padded from 514
#define SF_STRIDE_B 1152     // 576 fp16 per row; multiple of 128 B for XOR swizzle

// ws float-offsets
#define WS_R  0
#define WS_T  (WS_R + N*9)
#define WS_XS (WS_T + N*3)
#define WS_LI (WS_XS + N*15)
#define WS_LJ (WS_LI + N*128)
// ws byte-offsets (after 289792 floats)
#define WCT_OFF 1159168u     // 128*544 fp16  (WcatT[col][k])
#define W1T_OFF 1298432u     // 256*128 fp16  (w1T[col][k])
#define W2T_OFF 1363968u     // 128*256 fp16  (w2T[col][k])

typedef _Float16 half8 __attribute__((ext_vector_type(8)));
typedef float f32x16 __attribute__((ext_vector_type(16)));

__device__ __forceinline__ float gelu_tanh(float x) {
    float x3 = x * x * x;
    float u = 0.7978845608028654f * (x + 0.044715f * x3);
    return 0.5f * x * (1.0f + tanhf(u));
}

__global__ __launch_bounds__(256) void prep_kernel(
    const float* __restrict__ local_, const float* __restrict__ pos,
    const float* __restrict__ W_li, const float* __restrict__ W_lj,
    float* __restrict__ ws)
{
    const int n0 = blockIdx.x * 8;
    const int tid = threadIdx.x;
    __shared__ float sl[8][LOCALD];
    __shared__ float sR8[8][9];
    __shared__ float st8[8][3];

    for (int t = tid; t < 8 * LOCALD; t += 256) {
        int r = t >> 9, q = t & 511;
        sl[r][q] = local_[(size_t)(n0 + r) * LOCALD + q];
    }
    if (tid < 8) {
        int n = n0 + tid;
        const float* pp = pos + (size_t)n * 15;
        float nx = pp[0], ny = pp[1], nz = pp[2];
        float cax = pp[3], cay = pp[4], caz = pp[5];
        float cx = pp[6], cy = pp[7], cz = pp[8];
        float e1x = cx - cax, e1y = cy - cay, e1z = cz - caz;
        float inv1 = rsqrtf(e1x * e1x + e1y * e1y + e1z * e1z + 1e-8f);
        e1x *= inv1; e1y *= inv1; e1z *= inv1;
        float v2x = nx - cax, v2y = ny - cay, v2z = nz - caz;
        float dp = v2x * e1x + v2y * e1y + v2z * e1z;
        float e2x = v2x - dp * e1x, e2y = v2y - dp * e1y, e2z = v2z - dp * e1z;
        float inv2 = rsqrtf(e2x * e2x + e2y * e2y + e2z * e2z + 1e-8f);
        e2x *= inv2; e2y *= inv2; e2z *= inv2;
        float e3x = e1y * e2z - e1z * e2y;
        float e3y = e1z * e2x - e1x * e2z;
        float e3z = e1x * e2y - e1y * e2x;
        sR8[tid][0] = e1x; sR8[tid][1] = e2x; sR8[tid][2] = e3x;
        sR8[tid][3] = e1y; sR8[tid][4] = e2y; sR8[tid][5] = e3y;
        sR8[tid][6] = e1z; sR8[tid][7] = e2z; sR8[tid][8] = e3z;
        st8[tid][0] = cax; st8[tid][1] = cay; st8[tid][2] = caz;
        #pragma unroll
        for (int i = 0; i < 9; ++i) ws[WS_R + (size_t)n * 9 + i] = sR8[tid][i];
        #pragma unroll
        for (int i = 0; i < 3; ++i) ws[WS_T + (size_t)n * 3 + i] = st8[tid][i];
    }
    __syncthreads();

    for (int t = tid; t < 8 * 15; t += 256) {
        int r = t / 15, q = t % 15, a = q / 3, dd = q % 3;
        int n = n0 + r;
        const float* pp = pos + (size_t)n * 15 + a * 3;
        float v = sR8[r][0 * 3 + dd] * (pp[0] - st8[r][0])
                + sR8[r][1 * 3 + dd] * (pp[1] - st8[r][1])
                + sR8[r][2 * 3 + dd] * (pp[2] - st8[r][2]);
        ws[WS_XS + (size_t)n * 15 + q] = v;
    }

    const int c = tid & 127;
    const int hh = tid >> 7;
    const int r0 = hh * 4;
    float ali0 = 0, ali1 = 0, ali2 = 0, ali3 = 0;
    float alj0 = 0, alj1 = 0, alj2 = 0, alj3 = 0;
    const float* wli = W_li + c;
    const float* wlj = W_lj + c;
    __syncthreads();
    for (int f = 0; f < LOCALD; ++f) {
        float a_ = wli[(size_t)f * 128];
        float b_ = wlj[(size_t)f * 128];
        float l0 = sl[r0 + 0][f], l1 = sl[r0 + 1][f], l2 = sl[r0 + 2][f], l3 = sl[r0 + 3][f];
        ali0 += l0 * a_; ali1 += l1 * a_; ali2 += l2 * a_; ali3 += l3 * a_;
        alj0 += l0 * b_; alj1 += l1 * b_; alj2 += l2 * b_; alj3 += l3 * b_;
    }
    ws[WS_LI + (size_t)(n0 + r0 + 0) * 128 + c] = ali0;
    ws[WS_LI + (size_t)(n0 + r0 + 1) * 128 + c] = ali1;
    ws[WS_LI + (size_t)(n0 + r0 + 2) * 128 + c] = ali2;
    ws[WS_LI + (size_t)(n0 + r0 + 3) * 128 + c] = ali3;
    ws[WS_LJ + (size_t)(n0 + r0 + 0) * 128 + c] = alj0;
    ws[WS_LJ + (size_t)(n0 + r0 + 1) * 128 + c] = alj1;
    ws[WS_LJ + (size_t)(n0 + r0 + 2) * 128 + c] = alj2;
    ws[WS_LJ + (size_t)(n0 + r0 + 3) * 128 + c] = alj3;
}

// Convert + transpose weights to fp16: WcatT[128][544], w1T[256][128], w2T[128][256]
__global__ __launch_bounds__(256) void convw_kernel(
    const float* __restrict__ Wd, const float* __restrict__ Wdir,
    const float* __restrict__ Wrot, const float* __restrict__ Wv,
    const float* __restrict__ w1, const float* __restrict__ w2,
    char* __restrict__ wsb)
{
    _Float16* wct = (_Float16*)(wsb + WCT_OFF);
    _Float16* w1t = (_Float16*)(wsb + W1T_OFF);
    _Float16* w2t = (_Float16*)(wsb + W2T_OFF);
    int g = blockIdx.x * 256 + threadIdx.x;
    if (g < 128 * 544) {
        int c = g / 544, f = g % 544;
        float v = 0.0f;
        if (f < 400) v = Wd[(size_t)f * 128 + c];
        else if (f < 475) v = Wdir[(size_t)(f - 400) * 128 + c];
        else if (f < 484) v = Wrot[(size_t)(f - 475) * 128 + c];
        else if (f < 514) v = Wv[(size_t)(f - 484) * 128 + c];
        wct[g] = (_Float16)v;
    }
    int g2 = g - 128 * 544;
    if (g2 >= 0 && g2 < 256 * 128) {
        int c = g2 / 128, f = g2 % 128;
        w1t[g2] = (_Float16)w1[(size_t)f * 256 + c];
    }
    int g3 = g - 128 * 544 - 256 * 128;
    if (g3 >= 0 && g3 < 128 * 256) {
        int c = g3 / 256, f = g3 % 256;
        w2t[g3] = (_Float16)w2[(size_t)f * 128 + c];
    }
}

// swizzled fp16 LDS store into feature buffer
__device__ __forceinline__ void sfw(char* smem, int r, int f, float v) {
    int off = r * SF_STRIDE_B + ((f * 2) ^ ((r & 7) << 4));
    *(_Float16*)(smem + off) = (_Float16)v;
}

__global__ __launch_bounds__(256, 2) void main_kernel(
    const float* __restrict__ pair, const float* __restrict__ pos,
    const int* __restrict__ neigh, const int* __restrict__ mask,
    const float* __restrict__ ln_s, const float* __restrict__ ln_b,
    const float* __restrict__ b1, const float* __restrict__ b2,
    const float* __restrict__ ws, const char* __restrict__ wsb,
    float* __restrict__ out)
{
    const int R0 = blockIdx.x * ROWS;
    const int tid = threadIdx.x;
    const int lane = tid & 63;
    const int wv = tid >> 6;
    const int myrow = lane & 31;
    const int khalf = (lane >> 5) * 8;   // k-offset of this half-wave within a K=16 step

    __shared__ __align__(16) char smem[45184];
    int*   sn  = (int*)(smem + 36864);
    int*   sj  = (int*)(smem + 36992);
    float* spn = (float*)(smem + 37120);
    float* spj = (float*)(smem + 39040);
    float* srn = (float*)(smem + 40960);
    float* srj = (float*)(smem + 42112);
    float* sxs = (float*)(smem + 43264);

    // ---- issue B-fragment loads for GEMM1 early (held in registers) ----
    const _Float16* wct = (const _Float16*)(wsb + WCT_OFF);
    const int colbase = wv * 32 + myrow;
    half8 bw[34];
    #pragma unroll
    for (int ks = 0; ks < 34; ++ks)
        bw[ks] = *(const half8*)(wct + (size_t)colbase * FEATK + ks * 16 + khalf);

    // ---- zero feature buffer; stage row indices ----
    {
        uint4 z; z.x = z.y = z.z = z.w = 0u;
        uint4* zp = (uint4*)smem;
        for (int t = tid; t < 36864 / 16; t += 256) zp[t] = z;
    }
    if (tid < ROWS) {
        int Rg = R0 + tid;
        int n = Rg / K;
        int kk = Rg - n * K;
        int j = neigh[n * K + kk];
        if (j < 0) j += N;
        sn[tid] = n; sj[tid] = j;
    }
    __syncthreads();

    // ---- stage per-row geometry ----
    for (int t = tid; t < ROWS * 15; t += 256) {
        int r = t / 15, q = t % 15;
        spn[t] = pos[(size_t)sn[r] * 15 + q];
        spj[t] = pos[(size_t)sj[r] * 15 + q];
        sxs[t] = ws[WS_XS + (size_t)sn[r] * 15 + q];
    }
    for (int t = tid; t < ROWS * 9; t += 256) {
        int r = t / 9, q = t % 9;
        srn[t] = ws[WS_R + (size_t)sn[r] * 9 + q];
        srj[t] = ws[WS_R + (size_t)sj[r] * 9 + q];
    }
    __syncthreads();

    // ---- feature generation into swizzled fp16 LDS ----
    for (int t = tid; t < ROWS * 25; t += 256) {
        int r = t / 25, ab = t % 25, a = ab / 5, b = ab % 5;
        const float* Pn = spn + r * 15;
        const float* Pj = spj + r * 15;
        const float* Rn = srn + r * 9;
        float o0 = Pn[a * 3 + 0] - Pj[b * 3 + 0];
        float o1 = Pn[a * 3 + 1] - Pj[b * 3 + 1];
        float o2 = Pn[a * 3 + 2] - Pj[b * 3 + 2];
        float d = sqrtf(o0 * o0 + o1 * o1 + o2 * o2 + 1e-8f);
        const float inv_step = 16.0f / 22.0f;
        int base = a * 80 + b * 16;
        #pragma unroll
        for (int bin = 0; bin < 16; ++bin) {
            float cen = (22.0f / 15.0f) * bin;
            float z = (d - cen) * inv_step;
            sfw(smem, r, base + bin, __expf(-z * z));
        }
        float l0 = Rn[0] * o0 + Rn[3] * o1 + Rn[6] * o2;
        float l1 = Rn[1] * o0 + Rn[4] * o1 + Rn[7] * o2;
        float l2 = Rn[2] * o0 + Rn[5] * o1 + Rn[8] * o2;
        float inv = rsqrtf(l0 * l0 + l1 * l1 + l2 * l2 + 1e-8f);
        int dbase = 400 + a * 15 + b * 3;
        sfw(smem, r, dbase + 0, l0 * inv);
        sfw(smem, r, dbase + 1, l1 * inv);
        sfw(smem, r, dbase + 2, l2 * inv);
    }
    for (int t = tid; t < ROWS * 9; t += 256) {
        int r = t / 9, q = t % 9, i = q / 3, jd = q % 3;
        const float* Rn = srn + r * 9;
        const float* Rj = srj + r * 9;
        float v = Rn[0 * 3 + i] * Rj[0 * 3 + jd]
                + Rn[1 * 3 + i] * Rj[1 * 3 + jd]
                + Rn[2 * 3 + i] * Rj[2 * 3 + jd];
        sfw(smem, r, 475 + q, v);
    }
    for (int t = tid; t < ROWS * 15; t += 256) {
        int r = t / 15, q = t % 15, a = q / 3, dd = q % 3;
        const float* Pn = spn + r * 15;
        const float* Pj = spj + r * 15;
        const float* Rn = srn + r * 9;
        float xn = Rn[0 * 3 + dd] * (Pj[a * 3 + 0] - Pn[3])
                 + Rn[1 * 3 + dd] * (Pj[a * 3 + 1] - Pn[4])
                 + Rn[2 * 3 + dd] * (Pj[a * 3 + 2] - Pn[5]);
        sfw(smem, r, 484 + a * 6 + dd, 0.1f * sxs[r * 15 + q]);
        sfw(smem, r, 484 + a * 6 + 3 + dd, 0.1f * xn);
    }
    __syncthreads();

    // ---- GEMM1: feat[32 x 544] @ Wcat[544 x 128] via mfma 32x32x16, B in regs ----
    f32x16 acc0, acc1;
    #pragma unroll
    for (int q = 0; q < 16; ++q) { acc0[q] = 0.0f; acc1[q] = 0.0f; }
    #pragma unroll
    for (int ks = 0; ks < 34; ks += 2) {
        int k0 = ks * 16 + khalf;
        int k1 = (ks + 1) * 16 + khalf;
        half8 a0 = *(const half8*)(smem + myrow * SF_STRIDE_B + ((k0 * 2) ^ ((myrow & 7) << 4)));
        half8 a1 = *(const half8*)(smem + myrow * SF_STRIDE_B + ((k1 * 2) ^ ((myrow & 7) << 4)));
        acc0 = __builtin_amdgcn_mfma_f32_32x32x16_f16(a0, bw[ks], acc0, 0, 0, 0);
        acc1 = __builtin_amdgcn_mfma_f32_32x32x16_f16(a1, bw[ks + 1], acc1, 0, 0, 0);
    }
    __syncthreads();   // sfeat dead; smem[0:16K) becomes pbuf (fp32 [32][128])

    // ---- epilogue: + pair gather + li + lj -> pbuf ----
    #pragma unroll
    for (int q = 0; q < 16; ++q) {
        int rr = (q & 3) + 8 * (q >> 2) + 4 * (lane >> 5);
        int nq = sn[rr], jq = sj[rr];
        float v = acc0[q] + acc1[q]
                + pair[((size_t)nq * N + jq) * PAIRD + colbase]
                + ws[WS_LI + (size_t)nq * PAIRD + colbase]
                + ws[WS_LJ + (size_t)jq * PAIRD + colbase];
        *(float*)(smem + rr * 512 + colbase * 4) = v;
    }
    __syncthreads();

    // ---- LayerNorm: wave wv handles rows wv*8..wv*8+7; write pA fp16 @16384 ----
    {
        float lns0 = ln_s[lane], lns1 = ln_s[lane + 64];
        float lnb0 = ln_b[lane], lnb1 = ln_b[lane + 64];
        #pragma unroll
        for (int rr8 = 0; rr8 < 8; ++rr8) {
            int row = wv * 8 + rr8;
            float v0 = *(float*)(smem + row * 512 + lane * 4);
            float v1 = *(float*)(smem + row * 512 + (lane + 64) * 4);
            float s = v0 + v1, s2 = v0 * v0 + v1 * v1;
            #pragma unroll
            for (int o = 32; o > 0; o >>= 1) {
                s += __shfl_xor(s, o, 64);
                s2 += __shfl_xor(s2, o, 64);
            }
            float mu = s * (1.0f / 128.0f);
            float var = s2 * (1.0f / 128.0f) - mu * mu;
            float rs = rsqrtf(var + 1e-5f);
            int sw = (row & 7) << 4;
            *(_Float16*)(smem + 16384 + row * 256 + ((lane * 2) ^ sw)) =
                (_Float16)((v0 - mu) * rs * lns0 + lnb0);
            *(_Float16*)(smem + 16384 + row * 256 + (((lane + 64) * 2) ^ sw)) =
                (_Float16)((v1 - mu) * rs * lns1 + lnb1);
        }
    }
    __syncthreads();

    // ---- MLP1: pA[32x128] @ w1[128x256], wave cols [wv*64, wv*64+64) ----
    {
        const _Float16* w1t = (const _Float16*)(wsb + W1T_OFF);
        const int c0 = wv * 64 + myrow;
        const int c1 = c0 + 32;
        half8 wf0[8], wf1[8];
        #pragma unroll
        for (int ks = 0; ks < 8; ++ks) {
            wf0[ks] = *(const half8*)(w1t + (size_t)c0 * 128 + ks * 16 + khalf);
            wf1[ks] = *(const half8*)(w1t + (size_t)c1 * 128 + ks * 16 + khalf);
        }
        f32x16 h0, h1;
        #pragma unroll
        for (int q = 0; q < 16; ++q) { h0[q] = 0.0f; h1[q] = 0.0f; }
        #pragma unroll
        for (int ks = 0; ks < 8; ++ks) {
            int k0 = ks * 16 + khalf;
            half8 a = *(const half8*)(smem + 16384 + myrow * 256 + ((k0 * 2) ^ ((myrow & 7) << 4)));
            h0 = __builtin_amdgcn_mfma_f32_32x32x16_f16(a, wf0[ks], h0, 0, 0, 0);
            h1 = __builtin_amdgcn_mfma_f32_32x32x16_f16(a, wf1[ks], h1, 0, 0, 0);
        }
        float bb0 = b1[c0], bb1 = b1[c1];
        #pragma unroll
        for (int q = 0; q < 16; ++q) {
            int rr = (q & 3) + 8 * (q >> 2) + 4 * (lane >> 5);
            int sw = (rr & 7) << 4;
            *(_Float16*)(smem + rr * 512 + ((c0 * 2) ^ sw)) = (_Float16)gelu_tanh(h0[q] + bb0);
            *(_Float16*)(smem + rr * 512 + ((c1 * 2) ^ sw)) = (_Float16)gelu_tanh(h1[q] + bb1);
        }
    }
    __syncthreads();

    // ---- MLP2: hbuf[32x256] @ w2[256x128], wave cols [wv*32, wv*32+32) ----
    {
        const _Float16* w2t = (const _Float16*)(wsb + W2T_OFF);
        const int oc = wv * 32 + myrow;
        half8 w2f[16];
        #pragma unroll
        for (int ks = 0; ks < 16; ++ks)
            w2f[ks] = *(const half8*)(w2t + (size_t)oc * 256 + ks * 16 + khalf);
        f32x16 o0, o1;
        #pragma unroll
        for (int q = 0; q < 16; ++q) { o0[q] = 0.0f; o1[q] = 0.0f; }
        #pragma unroll
        for (int ks = 0; ks < 16; ks += 2) {
            int k0 = ks * 16 + khalf;
            int k1 = (ks + 1) * 16 + khalf;
            half8 a0 = *(const half8*)(smem + myrow * 512 + ((k0 * 2) ^ ((myrow & 7) << 4)));
            half8 a1 = *(const half8*)(smem + myrow * 512 + ((k1 * 2) ^ ((myrow & 7) << 4)));
            o0 = __builtin_amdgcn_mfma_f32_32x32x16_f16(a0, w2f[ks], o0, 0, 0, 0);
            o1 = __builtin_amdgcn_mfma_f32_32x32x16_f16(a1, w2f[ks + 1], o1, 0, 0, 0);
        }
        float bb = b2[oc];
        #pragma unroll
        for (int q = 0; q < 16; ++q) {
            int rr = (q & 3) + 8 * (q >> 2) + 4 * (lane >> 5);
            out[((size_t)(R0 + rr)) * PAIRD + oc] = o0[q] + o1[q] + bb;
        }
    }

    // ---- pair_mask ----
    if (tid < ROWS) {
        int Rg = R0 + tid;
        int n = Rg / K;
        int kk = Rg - n * K;
        int jr = neigh[n * K + kk];
        int jj = jr < 0 ? jr + N : jr;
        bool pm = (jr != -1) && (mask[n] != 0) && (mask[jj] != 0);
        out[(size_t)N * K * PAIRD + Rg] = pm ? 1.0f : 0.0f;
    }
}

extern "C" void kernel_launch(void* const* d_in, const int* in_sizes, int n_in,
                              void* d_out, int out_size, void* d_ws, size_t ws_size,
                              hipStream_t stream) {
    const float* local_ = (const float*)d_in[0];
    const float* pos = (const float*)d_in[1];
    const float* pair = (const float*)d_in[2];
    const int* neigh = (const int*)d_in[3];
    const int* mask = (const int*)d_in[4];
    const float* W_li = (const float*)d_in[5];
    const float* W_lj = (const float*)d_in[6];
    const float* W_dist = (const float*)d_in[7];
    const float* W_dir = (const float*)d_in[8];
    const float* W_rot = (const float*)d_in[9];
    const float* W_vec = (const float*)d_in[10];
    const float* ln_s = (const float*)d_in[11];
    const float* ln_b = (const float*)d_in[12];
    const float* w1 = (const float*)d_in[13];
    const float* b1 = (const float*)d_in[14];
    const float* w2 = (const float*)d_in[15];
    const float* b2 = (const float*)d_in[16];
    float* ws = (float*)d_ws;
    char* wsb = (char*)d_ws;
    float* out = (float*)d_out;

    hipLaunchKernelGGL(prep_kernel, dim3(N / 8), dim3(256), 0, stream,
                       local_, pos, W_li, W_lj, ws);
    hipLaunchKernelGGL(convw_kernel, dim3(528), dim3(256), 0, stream,
                       W_dist, W_dir, W_rot, W_vec, w1, w2, wsb);
    hipLaunchKernelGGL(main_kernel, dim3((N * K) / ROWS), dim3(256), 0, stream,
                       pair, pos, neigh, mask, ln_s, ln_b, b1, b2, ws, wsb, out);
}

// Round 5
// 112.818 us; speedup vs baseline: 3.1538x; 1.0934x over previous
//
#include <hip/hip_runtime.h>
#include <hip/hip_bf16.h>
#include <math.h>

#define N 1024
#define K 48
#define A 5
#define LOCALD 512
#define PAIRD 128
#define ROWS 32
#define FEATK 544            // 34 * 16, zero-padded from 514
#define SF_STRIDE_B 1152     // 576 fp16 per row; multiple of 128 B for XOR swizzle

// ws float-offsets
#define WS_R  0
#define WS_T  (WS_R + N*9)
#define WS_XS (WS_T + N*3)
#define WS_LI (WS_XS + N*15)
#define WS_LJ (WS_LI + N*128)
// ws byte-offsets (after 289792 floats)
#define WCT_OFF 1159168u     // 128*544 fp16  (WcatT[col][k])
#define W1T_OFF 1298432u     // 256*128 fp16  (w1T[col][k])
#define W2T_OFF 1363968u     // 128*256 fp16  (w2T[col][k])

typedef _Float16 half8 __attribute__((ext_vector_type(8)));
typedef float f32x16 __attribute__((ext_vector_type(16)));

// gelu(x) = 0.5x(1+tanh(u)) = x * sigmoid(2u),  u = 0.7978845608(x + 0.044715 x^3)
__device__ __forceinline__ float gelu_fast(float x) {
    float u2 = 1.5957691216057308f * x * (1.0f + 0.044715f * x * x);  // 2u
    float t = __expf(-u2);
    return x * __builtin_amdgcn_rcpf(1.0f + t);
}

// prep (blocks 0..127): frames/x_self/li/lj.  convw (blocks 128..655): fp16 weight transpose.
__global__ __launch_bounds__(256) void prep_kernel(
    const float* __restrict__ local_, const float* __restrict__ pos,
    const float* __restrict__ W_li, const float* __restrict__ W_lj,
    const float* __restrict__ Wd, const float* __restrict__ Wdir,
    const float* __restrict__ Wrot, const float* __restrict__ Wv,
    const float* __restrict__ w1, const float* __restrict__ w2,
    float* __restrict__ ws, char* __restrict__ wsb)
{
    const int tid = threadIdx.x;
    if (blockIdx.x >= 128) {
        // ---- convw part ----
        _Float16* wct = (_Float16*)(wsb + WCT_OFF);
        _Float16* w1t = (_Float16*)(wsb + W1T_OFF);
        _Float16* w2t = (_Float16*)(wsb + W2T_OFF);
        int g = (blockIdx.x - 128) * 256 + tid;
        if (g < 128 * 544) {
            int c = g / 544, f = g % 544;
            float v = 0.0f;
            if (f < 400) v = Wd[(size_t)f * 128 + c];
            else if (f < 475) v = Wdir[(size_t)(f - 400) * 128 + c];
            else if (f < 484) v = Wrot[(size_t)(f - 475) * 128 + c];
            else if (f < 514) v = Wv[(size_t)(f - 484) * 128 + c];
            wct[g] = (_Float16)v;
        }
        int g2 = g - 128 * 544;
        if (g2 >= 0 && g2 < 256 * 128) {
            int c = g2 / 128, f = g2 % 128;
            w1t[g2] = (_Float16)w1[(size_t)f * 256 + c];
        }
        int g3 = g - 128 * 544 - 256 * 128;
        if (g3 >= 0 && g3 < 128 * 256) {
            int c = g3 / 256, f = g3 % 256;
            w2t[g3] = (_Float16)w2[(size_t)f * 128 + c];
        }
        return;
    }

    const int n0 = blockIdx.x * 8;
    __shared__ float sl[8][LOCALD];
    __shared__ float sR8[8][9];
    __shared__ float st8[8][3];

    for (int t = tid; t < 8 * LOCALD; t += 256) {
        int r = t >> 9, q = t & 511;
        sl[r][q] = local_[(size_t)(n0 + r) * LOCALD + q];
    }
    if (tid < 8) {
        int n = n0 + tid;
        const float* pp = pos + (size_t)n * 15;
        float nx = pp[0], ny = pp[1], nz = pp[2];
        float cax = pp[3], cay = pp[4], caz = pp[5];
        float cx = pp[6], cy = pp[7], cz = pp[8];
        float e1x = cx - cax, e1y = cy - cay, e1z = cz - caz;
        float inv1 = rsqrtf(e1x * e1x + e1y * e1y + e1z * e1z + 1e-8f);
        e1x *= inv1; e1y *= inv1; e1z *= inv1;
        float v2x = nx - cax, v2y = ny - cay, v2z = nz - caz;
        float dp = v2x * e1x + v2y * e1y + v2z * e1z;
        float e2x = v2x - dp * e1x, e2y = v2y - dp * e1y, e2z = v2z - dp * e1z;
        float inv2 = rsqrtf(e2x * e2x + e2y * e2y + e2z * e2z + 1e-8f);
        e2x *= inv2; e2y *= inv2; e2z *= inv2;
        float e3x = e1y * e2z - e1z * e2y;
        float e3y = e1z * e2x - e1x * e2z;
        float e3z = e1x * e2y - e1y * e2x;
        sR8[tid][0] = e1x; sR8[tid][1] = e2x; sR8[tid][2] = e3x;
        sR8[tid][3] = e1y; sR8[tid][4] = e2y; sR8[tid][5] = e3y;
        sR8[tid][6] = e1z; sR8[tid][7] = e2z; sR8[tid][8] = e3z;
        st8[tid][0] = cax; st8[tid][1] = cay; st8[tid][2] = caz;
        #pragma unroll
        for (int i = 0; i < 9; ++i) ws[WS_R + (size_t)n * 9 + i] = sR8[tid][i];
        #pragma unroll
        for (int i = 0; i < 3; ++i) ws[WS_T + (size_t)n * 3 + i] = st8[tid][i];
    }
    __syncthreads();

    for (int t = tid; t < 8 * 15; t += 256) {
        int r = t / 15, q = t % 15, a = q / 3, dd = q % 3;
        int n = n0 + r;
        const float* pp = pos + (size_t)n * 15 + a * 3;
        float v = sR8[r][0 * 3 + dd] * (pp[0] - st8[r][0])
                + sR8[r][1 * 3 + dd] * (pp[1] - st8[r][1])
                + sR8[r][2 * 3 + dd] * (pp[2] - st8[r][2]);
        ws[WS_XS + (size_t)n * 15 + q] = v;
    }

    const int c = tid & 127;
    const int hh = tid >> 7;
    const int r0 = hh * 4;
    float ali0 = 0, ali1 = 0, ali2 = 0, ali3 = 0;
    float alj0 = 0, alj1 = 0, alj2 = 0, alj3 = 0;
    const float* wli = W_li + c;
    const float* wlj = W_lj + c;
    __syncthreads();
    #pragma unroll 4
    for (int f = 0; f < LOCALD; ++f) {
        float a_ = wli[(size_t)f * 128];
        float b_ = wlj[(size_t)f * 128];
        float l0 = sl[r0 + 0][f], l1 = sl[r0 + 1][f], l2 = sl[r0 + 2][f], l3 = sl[r0 + 3][f];
        ali0 += l0 * a_; ali1 += l1 * a_; ali2 += l2 * a_; ali3 += l3 * a_;
        alj0 += l0 * b_; alj1 += l1 * b_; alj2 += l2 * b_; alj3 += l3 * b_;
    }
    ws[WS_LI + (size_t)(n0 + r0 + 0) * 128 + c] = ali0;
    ws[WS_LI + (size_t)(n0 + r0 + 1) * 128 + c] = ali1;
    ws[WS_LI + (size_t)(n0 + r0 + 2) * 128 + c] = ali2;
    ws[WS_LI + (size_t)(n0 + r0 + 3) * 128 + c] = ali3;
    ws[WS_LJ + (size_t)(n0 + r0 + 0) * 128 + c] = alj0;
    ws[WS_LJ + (size_t)(n0 + r0 + 1) * 128 + c] = alj1;
    ws[WS_LJ + (size_t)(n0 + r0 + 2) * 128 + c] = alj2;
    ws[WS_LJ + (size_t)(n0 + r0 + 3) * 128 + c] = alj3;
}

// swizzled fp16 LDS store into feature buffer
__device__ __forceinline__ void sfw(char* smem, int r, int f, float v) {
    int off = r * SF_STRIDE_B + ((f * 2) ^ ((r & 7) << 4));
    *(_Float16*)(smem + off) = (_Float16)v;
}

__global__ __launch_bounds__(256, 2) void main_kernel(
    const float* __restrict__ pair, const float* __restrict__ pos,
    const int* __restrict__ neigh, const int* __restrict__ mask,
    const float* __restrict__ ln_s, const float* __restrict__ ln_b,
    const float* __restrict__ b1, const float* __restrict__ b2,
    const float* __restrict__ ws, const char* __restrict__ wsb,
    float* __restrict__ out)
{
    const int R0 = blockIdx.x * ROWS;
    const int tid = threadIdx.x;
    const int lane = tid & 63;
    const int wv = tid >> 6;
    const int myrow = lane & 31;
    const int khalf = (lane >> 5) * 8;   // k-offset of this half-wave within a K=16 step
    const int hi = lane >> 5;

    __shared__ __align__(16) char smem[45184];
    int*   sn  = (int*)(smem + 36864);
    int*   sj  = (int*)(smem + 36992);
    float* spn = (float*)(smem + 37120);
    float* spj = (float*)(smem + 39040);
    float* srn = (float*)(smem + 40960);
    float* srj = (float*)(smem + 42112);
    float* sxs = (float*)(smem + 43264);

    // ---- issue B-fragment loads for GEMM1 early (held in registers) ----
    const _Float16* wct = (const _Float16*)(wsb + WCT_OFF);
    const int colbase = wv * 32 + myrow;
    half8 bw[34];
    #pragma unroll
    for (int ks = 0; ks < 34; ++ks)
        bw[ks] = *(const half8*)(wct + (size_t)colbase * FEATK + ks * 16 + khalf);

    // ---- stage row indices ----
    if (tid < ROWS) {
        int Rg = R0 + tid;
        int n = Rg / K;
        int kk = Rg - n * K;
        int j = neigh[n * K + kk];
        if (j < 0) j += N;
        sn[tid] = n; sj[tid] = j;
    }
    __syncthreads();

    // ---- prefetch pair rows (HBM) + deduped li (only 2 distinct n per block) ----
    const int n0 = R0 / K;
    const int n1 = (n0 + 1 < N) ? n0 + 1 : n0;
    float li0 = ws[WS_LI + (size_t)n0 * PAIRD + colbase];
    float li1 = ws[WS_LI + (size_t)n1 * PAIRD + colbase];
    float pv[16];
    unsigned njmask = 0;
    #pragma unroll
    for (int q = 0; q < 16; ++q) {
        int rr = (q & 3) + 8 * (q >> 2) + 4 * hi;
        int nq = sn[rr], jq = sj[rr];
        pv[q] = pair[((size_t)nq * N + jq) * PAIRD + colbase];
        if (nq != n0) njmask |= (1u << q);
    }

    // ---- stage per-row geometry ----
    for (int t = tid; t < ROWS * 15; t += 256) {
        int r = t / 15, q = t % 15;
        spn[t] = pos[(size_t)sn[r] * 15 + q];
        spj[t] = pos[(size_t)sj[r] * 15 + q];
        sxs[t] = ws[WS_XS + (size_t)sn[r] * 15 + q];
    }
    for (int t = tid; t < ROWS * 9; t += 256) {
        int r = t / 9, q = t % 9;
        srn[t] = ws[WS_R + (size_t)sn[r] * 9 + q];
        srj[t] = ws[WS_R + (size_t)sj[r] * 9 + q];
    }
    __syncthreads();

    // ---- zero only the K-padding [514,544) per row ----
    for (int t = tid; t < ROWS * 30; t += 256) {
        int r = t / 30, f = 514 + t % 30;
        sfw(smem, r, f, 0.0f);
    }

    // ---- feature generation into swizzled fp16 LDS ----
    // RBF direct: z_i = (d - c*i)*s, z steps by -c*s = -16/15 per bin; 1 exp per bin.
    for (int t = tid; t < ROWS * 25; t += 256) {
        int r = t / 25, ab = t % 25, a = ab / 5, b = ab % 5;
        const float* Pn = spn + r * 15;
        const float* Pj = spj + r * 15;
        const float* Rn = srn + r * 9;
        float o0 = Pn[a * 3 + 0] - Pj[b * 3 + 0];
        float o1 = Pn[a * 3 + 1] - Pj[b * 3 + 1];
        float o2 = Pn[a * 3 + 2] - Pj[b * 3 + 2];
        float d = sqrtf(o0 * o0 + o1 * o1 + o2 * o2 + 1e-8f);
        float z = d * (16.0f / 22.0f);
        int base = a * 80 + b * 16;
        #pragma unroll
        for (int bin = 0; bin < 16; ++bin) {
            sfw(smem, r, base + bin, __expf(-z * z));
            z -= 1.0666666666666667f;   // 16/15
        }
        float l0 = Rn[0] * o0 + Rn[3] * o1 + Rn[6] * o2;
        float l1 = Rn[1] * o0 + Rn[4] * o1 + Rn[7] * o2;
        float l2 = Rn[2] * o0 + Rn[5] * o1 + Rn[8] * o2;
        float inv = rsqrtf(l0 * l0 + l1 * l1 + l2 * l2 + 1e-8f);
        int dbase = 400 + a * 15 + b * 3;
        sfw(smem, r, dbase + 0, l0 * inv);
        sfw(smem, r, dbase + 1, l1 * inv);
        sfw(smem, r, dbase + 2, l2 * inv);
    }
    for (int t = tid; t < ROWS * 9; t += 256) {
        int r = t / 9, q = t % 9, i = q / 3, jd = q % 3;
        const float* Rn = srn + r * 9;
        const float* Rj = srj + r * 9;
        float v = Rn[0 * 3 + i] * Rj[0 * 3 + jd]
                + Rn[1 * 3 + i] * Rj[1 * 3 + jd]
                + Rn[2 * 3 + i] * Rj[2 * 3 + jd];
        sfw(smem, r, 475 + q, v);
    }
    for (int t = tid; t < ROWS * 15; t += 256) {
        int r = t / 15, q = t % 15, a = q / 3, dd = q % 3;
        const float* Pn = spn + r * 15;
        const float* Pj = spj + r * 15;
        const float* Rn = srn + r * 9;
        float xn = Rn[0 * 3 + dd] * (Pj[a * 3 + 0] - Pn[3])
                 + Rn[1 * 3 + dd] * (Pj[a * 3 + 1] - Pn[4])
                 + Rn[2 * 3 + dd] * (Pj[a * 3 + 2] - Pn[5]);
        sfw(smem, r, 484 + a * 6 + dd, 0.1f * sxs[r * 15 + q]);
        sfw(smem, r, 484 + a * 6 + 3 + dd, 0.1f * xn);
    }
    __syncthreads();

    // ---- GEMM1: feat[32 x 544] @ Wcat[544 x 128] via mfma 32x32x16, B in regs ----
    f32x16 acc0, acc1;
    #pragma unroll
    for (int q = 0; q < 16; ++q) { acc0[q] = 0.0f; acc1[q] = 0.0f; }
    #pragma unroll
    for (int ks = 0; ks < 34; ks += 2) {
        int k0 = ks * 16 + khalf;
        int k1 = (ks + 1) * 16 + khalf;
        half8 a0 = *(const half8*)(smem + myrow * SF_STRIDE_B + ((k0 * 2) ^ ((myrow & 7) << 4)));
        half8 a1 = *(const half8*)(smem + myrow * SF_STRIDE_B + ((k1 * 2) ^ ((myrow & 7) << 4)));
        acc0 = __builtin_amdgcn_mfma_f32_32x32x16_f16(a0, bw[ks], acc0, 0, 0, 0);
        acc1 = __builtin_amdgcn_mfma_f32_32x32x16_f16(a1, bw[ks + 1], acc1, 0, 0, 0);
    }
    __syncthreads();   // sfeat dead; smem[0:16K) becomes pbuf (fp32 [32][128])

    // ---- epilogue: + prefetched pair + li + lj gather -> pbuf ----
    #pragma unroll
    for (int q = 0; q < 16; ++q) {
        int rr = (q & 3) + 8 * (q >> 2) + 4 * hi;
        int jq = sj[rr];
        float li = (njmask >> q) & 1 ? li1 : li0;
        float v = acc0[q] + acc1[q] + pv[q] + li
                + ws[WS_LJ + (size_t)jq * PAIRD + colbase];
        *(float*)(smem + rr * 512 + colbase * 4) = v;
    }
    __syncthreads();

    // ---- LayerNorm: wave wv handles rows wv*8..wv*8+7; write pA fp16 @16384 ----
    {
        float lns0 = ln_s[lane], lns1 = ln_s[lane + 64];
        float lnb0 = ln_b[lane], lnb1 = ln_b[lane + 64];
        #pragma unroll
        for (int rr8 = 0; rr8 < 8; ++rr8) {
            int row = wv * 8 + rr8;
            float v0 = *(float*)(smem + row * 512 + lane * 4);
            float v1 = *(float*)(smem + row * 512 + (lane + 64) * 4);
            float s = v0 + v1, s2 = v0 * v0 + v1 * v1;
            #pragma unroll
            for (int o = 32; o > 0; o >>= 1) {
                s += __shfl_xor(s, o, 64);
                s2 += __shfl_xor(s2, o, 64);
            }
            float mu = s * (1.0f / 128.0f);
            float var = s2 * (1.0f / 128.0f) - mu * mu;
            float rs = rsqrtf(var + 1e-5f);
            int sw = (row & 7) << 4;
            *(_Float16*)(smem + 16384 + row * 256 + ((lane * 2) ^ sw)) =
                (_Float16)((v0 - mu) * rs * lns0 + lnb0);
            *(_Float16*)(smem + 16384 + row * 256 + (((lane + 64) * 2) ^ sw)) =
                (_Float16)((v1 - mu) * rs * lns1 + lnb1);
        }
    }
    __syncthreads();

    // ---- MLP1: pA[32x128] @ w1[128x256], wave cols [wv*64, wv*64+64) ----
    {
        const _Float16* w1t = (const _Float16*)(wsb + W1T_OFF);
        const int c0 = wv * 64 + myrow;
        const int c1 = c0 + 32;
        half8 wf0[8], wf1[8];
        #pragma unroll
        for (int ks = 0; ks < 8; ++ks) {
            wf0[ks] = *(const half8*)(w1t + (size_t)c0 * 128 + ks * 16 + khalf);
            wf1[ks] = *(const half8*)(w1t + (size_t)c1 * 128 + ks * 16 + khalf);
        }
        f32x16 h0, h1;
        #pragma unroll
        for (int q = 0; q < 16; ++q) { h0[q] = 0.0f; h1[q] = 0.0f; }
        #pragma unroll
        for (int ks = 0; ks < 8; ++ks) {
            int k0 = ks * 16 + khalf;
            half8 a = *(const half8*)(smem + 16384 + myrow * 256 + ((k0 * 2) ^ ((myrow & 7) << 4)));
            h0 = __builtin_amdgcn_mfma_f32_32x32x16_f16(a, wf0[ks], h0, 0, 0, 0);
            h1 = __builtin_amdgcn_mfma_f32_32x32x16_f16(a, wf1[ks], h1, 0, 0, 0);
        }
        float bb0 = b1[c0], bb1 = b1[c1];
        #pragma unroll
        for (int q = 0; q < 16; ++q) {
            int rr = (q & 3) + 8 * (q >> 2) + 4 * hi;
            int sw = (rr & 7) << 4;
            *(_Float16*)(smem + rr * 512 + ((c0 * 2) ^ sw)) = (_Float16)gelu_fast(h0[q] + bb0);
            *(_Float16*)(smem + rr * 512 + ((c1 * 2) ^ sw)) = (_Float16)gelu_fast(h1[q] + bb1);
        }
    }
    __syncthreads();

    // ---- MLP2: hbuf[32x256] @ w2[256x128], wave cols [wv*32, wv*32+32) ----
    {
        const _Float16* w2t = (const _Float16*)(wsb + W2T_OFF);
        const int oc = wv * 32 + myrow;
        half8 w2f[16];
        #pragma unroll
        for (int ks = 0; ks < 16; ++ks)
            w2f[ks] = *(const half8*)(w2t + (size_t)oc * 256 + ks * 16 + khalf);
        f32x16 o0, o1;
        #pragma unroll
        for (int q = 0; q < 16; ++q) { o0[q] = 0.0f; o1[q] = 0.0f; }
        #pragma unroll
        for (int ks = 0; ks < 16; ks += 2) {
            int k0 = ks * 16 + khalf;
            int k1 = (ks + 1) * 16 + khalf;
            half8 a0 = *(const half8*)(smem + myrow * 512 + ((k0 * 2) ^ ((myrow & 7) << 4)));
            half8 a1 = *(const half8*)(smem + myrow * 512 + ((k1 * 2) ^ ((myrow & 7) << 4)));
            o0 = __builtin_amdgcn_mfma_f32_32x32x16_f16(a0, w2f[ks], o0, 0, 0, 0);
            o1 = __builtin_amdgcn_mfma_f32_32x32x16_f16(a1, w2f[ks + 1], o1, 0, 0, 0);
        }
        float bb = b2[oc];
        #pragma unroll
        for (int q = 0; q < 16; ++q) {
            int rr = (q & 3) + 8 * (q >> 2) + 4 * hi;
            out[((size_t)(R0 + rr)) * PAIRD + oc] = o0[q] + o1[q] + bb;
        }
    }

    // ---- pair_mask ----
    if (tid < ROWS) {
        int Rg = R0 + tid;
        int n = Rg / K;
        int kk = Rg - n * K;
        int jr = neigh[n * K + kk];
        int jj = jr < 0 ? jr + N : jr;
        bool pm = (jr != -1) && (mask[n] != 0) && (mask[jj] != 0);
        out[(size_t)N * K * PAIRD + Rg] = pm ? 1.0f : 0.0f;
    }
}

extern "C" void kernel_launch(void* const* d_in, const int* in_sizes, int n_in,
                              void* d_out, int out_size, void* d_ws, size_t ws_size,
                              hipStream_t stream) {
    const float* local_ = (const float*)d_in[0];
    const float* pos = (const float*)d_in[1];
    const float* pair = (const float*)d_in[2];
    const int* neigh = (const int*)d_in[3];
    const int* mask = (const int*)d_in[4];
    const float* W_li = (const float*)d_in[5];
    const float* W_lj = (const float*)d_in[6];
    const float* W_dist = (const float*)d_in[7];
    const float* W_dir = (const float*)d_in[8];
    const float* W_rot = (const float*)d_in[9];
    const float* W_vec = (const float*)d_in[10];
    const float* ln_s = (const float*)d_in[11];
    const float* ln_b = (const float*)d_in[12];
    const float* w1 = (const float*)d_in[13];
    const float* b1 = (const float*)d_in[14];
    const float* w2 = (const float*)d_in[15];
    const float* b2 = (const float*)d_in[16];
    float* ws = (float*)d_ws;
    char* wsb = (char*)d_ws;
    float* out = (float*)d_out;

    hipLaunchKernelGGL(prep_kernel, dim3(128 + 528), dim3(256), 0, stream,
                       local_, pos, W_li, W_lj, W_dist, W_dir, W_rot, W_vec,
                       w1, w2, ws, wsb);
    hipLaunchKernelGGL(main_kernel, dim3((N * K) / ROWS), dim3(256), 0, stream,
                       pair, pos, neigh, mask, ln_s, ln_b, b1, b2, ws, wsb, out);
}

// Round 6
// 82.060 us; speedup vs baseline: 4.3359x; 1.3748x over previous
//
#include <hip/hip_runtime.h>
#include <hip/hip_bf16.h>
#include <math.h>

#define N 1024
#define K 48
#define A 5
#define LOCALD 512
#define PAIRD 128
#define ROWS 32
#define FEATK 544            // 34 * 16, zero-padded from 514
#define SF_STRIDE_B 1152     // 576 fp16 per row; multiple of 128 B for XOR swizzle

// ws float-offsets
#define WS_R  0
#define WS_T  (WS_R + N*9)
#define WS_XS (WS_T + N*3)
#define WS_LI (WS_XS + N*15)
#define WS_LJ (WS_LI + N*128)
// ws byte-offsets (after 289792 floats)
#define WCT_OFF 1159168u     // 128*544 fp16  (WcatT[col][k])
#define W1T_OFF 1298432u     // 256*128 fp16  (w1T[col][k])
#define W2T_OFF 1363968u     // 128*256 fp16  (w2T[col][k])

typedef _Float16 half8 __attribute__((ext_vector_type(8)));
typedef float f32x16 __attribute__((ext_vector_type(16)));

// gelu(x) = 0.5x(1+tanh(u)) = x * sigmoid(2u),  u = 0.7978845608(x + 0.044715 x^3)
__device__ __forceinline__ float gelu_fast(float x) {
    float u2 = 1.5957691216057308f * x * (1.0f + 0.044715f * x * x);  // 2u
    float t = __expf(-u2);
    return x * __builtin_amdgcn_rcpf(1.0f + t);
}

// prep (blocks 0..255, 4 rows each): frames/x_self/li/lj.
// convw (blocks 256..783): fp16 weight transpose, coalesced reads.
__global__ __launch_bounds__(256) void prep_kernel(
    const float* __restrict__ local_, const float* __restrict__ pos,
    const float* __restrict__ W_li, const float* __restrict__ W_lj,
    const float* __restrict__ Wd, const float* __restrict__ Wdir,
    const float* __restrict__ Wrot, const float* __restrict__ Wv,
    const float* __restrict__ w1, const float* __restrict__ w2,
    float* __restrict__ ws, char* __restrict__ wsb)
{
    const int tid = threadIdx.x;
    if (blockIdx.x >= 256) {
        // ---- convw: coalesced source reads, scattered fp16 writes ----
        _Float16* wct = (_Float16*)(wsb + WCT_OFF);
        _Float16* w1t = (_Float16*)(wsb + W1T_OFF);
        _Float16* w2t = (_Float16*)(wsb + W2T_OFF);
        int g = (blockIdx.x - 256) * 256 + tid;
        if (g < 128 * 544) {
            int c = g & 127, f = g >> 7;            // read coalesced over c
            float v = 0.0f;
            if (f < 400) v = Wd[(size_t)f * 128 + c];
            else if (f < 475) v = Wdir[(size_t)(f - 400) * 128 + c];
            else if (f < 484) v = Wrot[(size_t)(f - 475) * 128 + c];
            else if (f < 514) v = Wv[(size_t)(f - 484) * 128 + c];
            wct[(size_t)c * FEATK + f] = (_Float16)v;
        } else {
            int g2 = g - 128 * 544;
            if (g2 < 256 * 128) {
                int c = g2 & 255, f = g2 >> 8;      // read w1 coalesced
                w1t[(size_t)c * 128 + f] = (_Float16)w1[(size_t)f * 256 + c];
            } else {
                int g3 = g2 - 256 * 128;
                if (g3 < 128 * 256) {
                    int c = g3 & 127, f = g3 >> 7;  // read w2 coalesced
                    w2t[(size_t)c * 256 + f] = (_Float16)w2[(size_t)f * 128 + c];
                }
            }
        }
        return;
    }

    const int n0 = blockIdx.x * 4;
    __shared__ float sl[4][LOCALD];
    __shared__ float sR4[4][9];
    __shared__ float st4[4][3];

    for (int t = tid; t < 4 * LOCALD; t += 256) {
        int r = t >> 9, q = t & 511;
        sl[r][q] = local_[(size_t)(n0 + r) * LOCALD + q];
    }
    if (tid < 4) {
        int n = n0 + tid;
        const float* pp = pos + (size_t)n * 15;
        float nx = pp[0], ny = pp[1], nz = pp[2];
        float cax = pp[3], cay = pp[4], caz = pp[5];
        float cx = pp[6], cy = pp[7], cz = pp[8];
        float e1x = cx - cax, e1y = cy - cay, e1z = cz - caz;
        float inv1 = rsqrtf(e1x * e1x + e1y * e1y + e1z * e1z + 1e-8f);
        e1x *= inv1; e1y *= inv1; e1z *= inv1;
        float v2x = nx - cax, v2y = ny - cay, v2z = nz - caz;
        float dp = v2x * e1x + v2y * e1y + v2z * e1z;
        float e2x = v2x - dp * e1x, e2y = v2y - dp * e1y, e2z = v2z - dp * e1z;
        float inv2 = rsqrtf(e2x * e2x + e2y * e2y + e2z * e2z + 1e-8f);
        e2x *= inv2; e2y *= inv2; e2z *= inv2;
        float e3x = e1y * e2z - e1z * e2y;
        float e3y = e1z * e2x - e1x * e2z;
        float e3z = e1x * e2y - e1y * e2x;
        sR4[tid][0] = e1x; sR4[tid][1] = e2x; sR4[tid][2] = e3x;
        sR4[tid][3] = e1y; sR4[tid][4] = e2y; sR4[tid][5] = e3y;
        sR4[tid][6] = e1z; sR4[tid][7] = e2z; sR4[tid][8] = e3z;
        st4[tid][0] = cax; st4[tid][1] = cay; st4[tid][2] = caz;
        #pragma unroll
        for (int i = 0; i < 9; ++i) ws[WS_R + (size_t)n * 9 + i] = sR4[tid][i];
        #pragma unroll
        for (int i = 0; i < 3; ++i) ws[WS_T + (size_t)n * 3 + i] = st4[tid][i];
    }
    __syncthreads();

    for (int t = tid; t < 4 * 15; t += 256) {
        int r = t / 15, q = t % 15, a = q / 3, dd = q % 3;
        int n = n0 + r;
        const float* pp = pos + (size_t)n * 15 + a * 3;
        float v = sR4[r][0 * 3 + dd] * (pp[0] - st4[r][0])
                + sR4[r][1 * 3 + dd] * (pp[1] - st4[r][1])
                + sR4[r][2 * 3 + dd] * (pp[2] - st4[r][2]);
        ws[WS_XS + (size_t)n * 15 + q] = v;
    }

    // li/lj: each half-block (128 ch) accumulates 2 rows
    const int c = tid & 127;
    const int hh = tid >> 7;
    const int r0 = hh * 2;
    float ali0 = 0, ali1 = 0, alj0 = 0, alj1 = 0;
    const float* wli = W_li + c;
    const float* wlj = W_lj + c;
    #pragma unroll 8
    for (int f = 0; f < LOCALD; ++f) {
        float a_ = wli[(size_t)f * 128];
        float b_ = wlj[(size_t)f * 128];
        float l0 = sl[r0 + 0][f], l1 = sl[r0 + 1][f];
        ali0 += l0 * a_; ali1 += l1 * a_;
        alj0 += l0 * b_; alj1 += l1 * b_;
    }
    ws[WS_LI + (size_t)(n0 + r0 + 0) * 128 + c] = ali0;
    ws[WS_LI + (size_t)(n0 + r0 + 1) * 128 + c] = ali1;
    ws[WS_LJ + (size_t)(n0 + r0 + 0) * 128 + c] = alj0;
    ws[WS_LJ + (size_t)(n0 + r0 + 1) * 128 + c] = alj1;
}

// swizzled fp16 LDS store into feature buffer
__device__ __forceinline__ void sfw(char* smem, int r, int f, float v) {
    int off = r * SF_STRIDE_B + ((f * 2) ^ ((r & 7) << 4));
    *(_Float16*)(smem + off) = (_Float16)v;
}

__global__ __launch_bounds__(256, 3) void main_kernel(
    const float* __restrict__ pair, const float* __restrict__ pos,
    const int* __restrict__ neigh, const int* __restrict__ mask,
    const float* __restrict__ ln_s, const float* __restrict__ ln_b,
    const float* __restrict__ b1, const float* __restrict__ b2,
    const float* __restrict__ ws, const char* __restrict__ wsb,
    float* __restrict__ out)
{
    const int R0 = blockIdx.x * ROWS;
    const int tid = threadIdx.x;
    const int lane = tid & 63;
    const int wv = tid >> 6;
    const int myrow = lane & 31;
    const int khalf = (lane >> 5) * 8;   // k-offset of this half-wave within a K=16 step
    const int hi = lane >> 5;
    const int swz = (myrow & 7) << 4;

    __shared__ __align__(16) char smem[45184];
    int*   sn  = (int*)(smem + 36864);
    int*   sj  = (int*)(smem + 36992);
    float* spn = (float*)(smem + 37120);
    float* spj = (float*)(smem + 39040);
    float* srn = (float*)(smem + 40960);
    float* srj = (float*)(smem + 42112);
    float* sxs = (float*)(smem + 43264);

    const _Float16* wct = (const _Float16*)(wsb + WCT_OFF);
    const int colbase = wv * 32 + myrow;

    // ---- stage row indices ----
    if (tid < ROWS) {
        int Rg = R0 + tid;
        int n = Rg / K;
        int kk = Rg - n * K;
        int j = neigh[n * K + kk];
        if (j < 0) j += N;
        sn[tid] = n; sj[tid] = j;
    }
    __syncthreads();

    // ---- prefetch pair + li + lj fully into pv (all scattered loads issued here,
    //      latency hidden under feature-gen) ----
    const int n0 = R0 / K;
    const int n1 = (n0 + 1 < N) ? n0 + 1 : n0;
    float li0 = ws[WS_LI + (size_t)n0 * PAIRD + colbase];
    float li1 = ws[WS_LI + (size_t)n1 * PAIRD + colbase];
    float pv[16];
    #pragma unroll
    for (int q = 0; q < 16; ++q) {
        int rr = (q & 3) + 8 * (q >> 2) + 4 * hi;
        int nq = sn[rr], jq = sj[rr];
        float li = (nq == n0) ? li0 : li1;
        pv[q] = pair[((size_t)nq * N + jq) * PAIRD + colbase]
              + ws[WS_LJ + (size_t)jq * PAIRD + colbase] + li;
    }

    // ---- stage per-row geometry ----
    for (int t = tid; t < ROWS * 15; t += 256) {
        int r = t / 15, q = t % 15;
        spn[t] = pos[(size_t)sn[r] * 15 + q];
        spj[t] = pos[(size_t)sj[r] * 15 + q];
        sxs[t] = ws[WS_XS + (size_t)sn[r] * 15 + q];
    }
    for (int t = tid; t < ROWS * 9; t += 256) {
        int r = t / 9, q = t % 9;
        srn[t] = ws[WS_R + (size_t)sn[r] * 9 + q];
        srj[t] = ws[WS_R + (size_t)sj[r] * 9 + q];
    }
    __syncthreads();

    // ---- zero only the K-padding [514,544) per row ----
    for (int t = tid; t < ROWS * 30; t += 256) {
        int r = t / 30, f = 514 + t % 30;
        sfw(smem, r, f, 0.0f);
    }

    // ---- feature generation into swizzled fp16 LDS ----
    for (int t = tid; t < ROWS * 25; t += 256) {
        int r = t / 25, ab = t % 25, a = ab / 5, b = ab % 5;
        const float* Pn = spn + r * 15;
        const float* Pj = spj + r * 15;
        const float* Rn = srn + r * 9;
        float o0 = Pn[a * 3 + 0] - Pj[b * 3 + 0];
        float o1 = Pn[a * 3 + 1] - Pj[b * 3 + 1];
        float o2 = Pn[a * 3 + 2] - Pj[b * 3 + 2];
        float d = sqrtf(o0 * o0 + o1 * o1 + o2 * o2 + 1e-8f);
        float z = d * (16.0f / 22.0f);
        int base = a * 80 + b * 16;
        int rb = r * SF_STRIDE_B;
        int rsw = (r & 7) << 4;
        #pragma unroll
        for (int bp = 0; bp < 8; ++bp) {
            float e0 = __expf(-z * z);
            float z1 = z - 1.0666666666666667f;
            float e1 = __expf(-z1 * z1);
            z = z1 - 1.0666666666666667f;
            union { _Float16 h[2]; unsigned u; } pk;
            pk.h[0] = (_Float16)e0; pk.h[1] = (_Float16)e1;
            int off = rb + (((base + bp * 2) * 2) ^ rsw);
            *(unsigned*)(smem + off) = pk.u;
        }
        float l0 = Rn[0] * o0 + Rn[3] * o1 + Rn[6] * o2;
        float l1 = Rn[1] * o0 + Rn[4] * o1 + Rn[7] * o2;
        float l2 = Rn[2] * o0 + Rn[5] * o1 + Rn[8] * o2;
        float inv = rsqrtf(l0 * l0 + l1 * l1 + l2 * l2 + 1e-8f);
        int dbase = 400 + a * 15 + b * 3;
        sfw(smem, r, dbase + 0, l0 * inv);
        sfw(smem, r, dbase + 1, l1 * inv);
        sfw(smem, r, dbase + 2, l2 * inv);
    }
    for (int t = tid; t < ROWS * 9; t += 256) {
        int r = t / 9, q = t % 9, i = q / 3, jd = q % 3;
        const float* Rn = srn + r * 9;
        const float* Rj = srj + r * 9;
        float v = Rn[0 * 3 + i] * Rj[0 * 3 + jd]
                + Rn[1 * 3 + i] * Rj[1 * 3 + jd]
                + Rn[2 * 3 + i] * Rj[2 * 3 + jd];
        sfw(smem, r, 475 + q, v);
    }
    for (int t = tid; t < ROWS * 15; t += 256) {
        int r = t / 15, q = t % 15, a = q / 3, dd = q % 3;
        const float* Pn = spn + r * 15;
        const float* Pj = spj + r * 15;
        const float* Rn = srn + r * 9;
        float xn = Rn[0 * 3 + dd] * (Pj[a * 3 + 0] - Pn[3])
                 + Rn[1 * 3 + dd] * (Pj[a * 3 + 1] - Pn[4])
                 + Rn[2 * 3 + dd] * (Pj[a * 3 + 2] - Pn[5]);
        sfw(smem, r, 484 + a * 6 + dd, 0.1f * sxs[r * 15 + q]);
        sfw(smem, r, 484 + a * 6 + 3 + dd, 0.1f * xn);
    }
    __syncthreads();

    // ---- GEMM1: feat[32 x 544] @ Wcat[544 x 128]; B streamed from L2 in-loop ----
    f32x16 acc0, acc1;
    #pragma unroll
    for (int q = 0; q < 16; ++q) { acc0[q] = 0.0f; acc1[q] = 0.0f; }
    {
        const _Float16* wp = wct + (size_t)colbase * FEATK + khalf;
        #pragma unroll
        for (int ks = 0; ks < 34; ks += 2) {
            half8 b0 = *(const half8*)(wp + ks * 16);
            half8 b1 = *(const half8*)(wp + (ks + 1) * 16);
            int k0 = ks * 16 + khalf;
            int k1 = (ks + 1) * 16 + khalf;
            half8 a0 = *(const half8*)(smem + myrow * SF_STRIDE_B + ((k0 * 2) ^ swz));
            half8 a1 = *(const half8*)(smem + myrow * SF_STRIDE_B + ((k1 * 2) ^ swz));
            acc0 = __builtin_amdgcn_mfma_f32_32x32x16_f16(a0, b0, acc0, 0, 0, 0);
            acc1 = __builtin_amdgcn_mfma_f32_32x32x16_f16(a1, b1, acc1, 0, 0, 0);
        }
    }
    __syncthreads();   // sfeat dead; smem[0:16K) becomes pbuf (fp32 [32][128])

    // ---- epilogue: acc + prefetched (pair+li+lj) -> pbuf ----
    #pragma unroll
    for (int q = 0; q < 16; ++q) {
        int rr = (q & 3) + 8 * (q >> 2) + 4 * hi;
        *(float*)(smem + rr * 512 + colbase * 4) = acc0[q] + acc1[q] + pv[q];
    }
    __syncthreads();

    // ---- LayerNorm: wave wv handles rows wv*8..wv*8+7; write pA fp16 @16384 ----
    {
        float lns0 = ln_s[lane], lns1 = ln_s[lane + 64];
        float lnb0 = ln_b[lane], lnb1 = ln_b[lane + 64];
        #pragma unroll
        for (int rr8 = 0; rr8 < 8; ++rr8) {
            int row = wv * 8 + rr8;
            float v0 = *(float*)(smem + row * 512 + lane * 4);
            float v1 = *(float*)(smem + row * 512 + (lane + 64) * 4);
            float s = v0 + v1, s2 = v0 * v0 + v1 * v1;
            #pragma unroll
            for (int o = 32; o > 0; o >>= 1) {
                s += __shfl_xor(s, o, 64);
                s2 += __shfl_xor(s2, o, 64);
            }
            float mu = s * (1.0f / 128.0f);
            float var = s2 * (1.0f / 128.0f) - mu * mu;
            float rs = rsqrtf(var + 1e-5f);
            int sw = (row & 7) << 4;
            *(_Float16*)(smem + 16384 + row * 256 + ((lane * 2) ^ sw)) =
                (_Float16)((v0 - mu) * rs * lns0 + lnb0);
            *(_Float16*)(smem + 16384 + row * 256 + (((lane + 64) * 2) ^ sw)) =
                (_Float16)((v1 - mu) * rs * lns1 + lnb1);
        }
    }
    __syncthreads();

    // ---- MLP1: pA[32x128] @ w1[128x256], wave cols [wv*64, wv*64+64) ----
    {
        const _Float16* w1t = (const _Float16*)(wsb + W1T_OFF);
        const int c0 = wv * 64 + myrow;
        const int c1 = c0 + 32;
        half8 wf0[8], wf1[8];
        #pragma unroll
        for (int ks = 0; ks < 8; ++ks) {
            wf0[ks] = *(const half8*)(w1t + (size_t)c0 * 128 + ks * 16 + khalf);
            wf1[ks] = *(const half8*)(w1t + (size_t)c1 * 128 + ks * 16 + khalf);
        }
        f32x16 h0, h1;
        #pragma unroll
        for (int q = 0; q < 16; ++q) { h0[q] = 0.0f; h1[q] = 0.0f; }
        #pragma unroll
        for (int ks = 0; ks < 8; ++ks) {
            int k0 = ks * 16 + khalf;
            half8 a = *(const half8*)(smem + 16384 + myrow * 256 + ((k0 * 2) ^ swz));
            h0 = __builtin_amdgcn_mfma_f32_32x32x16_f16(a, wf0[ks], h0, 0, 0, 0);
            h1 = __builtin_amdgcn_mfma_f32_32x32x16_f16(a, wf1[ks], h1, 0, 0, 0);
        }
        float bb0 = b1[c0], bb1 = b1[c1];
        #pragma unroll
        for (int q = 0; q < 16; ++q) {
            int rr = (q & 3) + 8 * (q >> 2) + 4 * hi;
            int sw = (rr & 7) << 4;
            *(_Float16*)(smem + rr * 512 + ((c0 * 2) ^ sw)) = (_Float16)gelu_fast(h0[q] + bb0);
            *(_Float16*)(smem + rr * 512 + ((c1 * 2) ^ sw)) = (_Float16)gelu_fast(h1[q] + bb1);
        }
    }
    __syncthreads();

    // ---- MLP2: hbuf[32x256] @ w2[256x128], wave cols [wv*32, wv*32+32) ----
    {
        const _Float16* w2t = (const _Float16*)(wsb + W2T_OFF);
        const int oc = wv * 32 + myrow;
        half8 w2f[16];
        #pragma unroll
        for (int ks = 0; ks < 16; ++ks)
            w2f[ks] = *(const half8*)(w2t + (size_t)oc * 256 + ks * 16 + khalf);
        f32x16 o0, o1;
        #pragma unroll
        for (int q = 0; q < 16; ++q) { o0[q] = 0.0f; o1[q] = 0.0f; }
        #pragma unroll
        for (int ks = 0; ks < 16; ks += 2) {
            int k0 = ks * 16 + khalf;
            int k1 = (ks + 1) * 16 + khalf;
            half8 a0 = *(const half8*)(smem + myrow * 512 + ((k0 * 2) ^ swz));
            half8 a1 = *(const half8*)(smem + myrow * 512 + ((k1 * 2) ^ swz));
            o0 = __builtin_amdgcn_mfma_f32_32x32x16_f16(a0, w2f[ks], o0, 0, 0, 0);
            o1 = __builtin_amdgcn_mfma_f32_32x32x16_f16(a1, w2f[ks + 1], o1, 0, 0, 0);
        }
        float bb = b2[oc];
        #pragma unroll
        for (int q = 0; q < 16; ++q) {
            int rr = (q & 3) + 8 * (q >> 2) + 4 * hi;
            out[((size_t)(R0 + rr)) * PAIRD + oc] = o0[q] + o1[q] + bb;
        }
    }

    // ---- pair_mask ----
    if (tid < ROWS) {
        int Rg = R0 + tid;
        int n = Rg / K;
        int kk = Rg - n * K;
        int jr = neigh[n * K + kk];
        int jj = jr < 0 ? jr + N : jr;
        bool pm = (jr != -1) && (mask[n] != 0) && (mask[jj] != 0);
        out[(size_t)N * K * PAIRD + Rg] = pm ? 1.0f : 0.0f;
    }
}

extern "C" void kernel_launch(void* const* d_in, const int* in_sizes, int n_in,
                              void* d_out, int out_size, void* d_ws, size_t ws_size,
                              hipStream_t stream) {
    const float* local_ = (const float*)d_in[0];
    const float* pos = (const float*)d_in[1];
    const float* pair = (const float*)d_in[2];
    const int* neigh = (const int*)d_in[3];
    const int* mask = (const int*)d_in[4];
    const float* W_li = (const float*)d_in[5];
    const float* W_lj = (const float*)d_in[6];
    const float* W_dist = (const float*)d_in[7];
    const float* W_dir = (const float*)d_in[8];
    const float* W_rot = (const float*)d_in[9];
    const float* W_vec = (const float*)d_in[10];
    const float* ln_s = (const float*)d_in[11];
    const float* ln_b = (const float*)d_in[12];
    const float* w1 = (const float*)d_in[13];
    const float* b1 = (const float*)d_in[14];
    const float* w2 = (const float*)d_in[15];
    const float* b2 = (const float*)d_in[16];
    float* ws = (float*)d_ws;
    char* wsb = (char*)d_ws;
    float* out = (float*)d_out;

    hipLaunchKernelGGL(prep_kernel, dim3(256 + 528), dim3(256), 0, stream,
                       local_, pos, W_li, W_lj, W_dist, W_dir, W_rot, W_vec,
                       w1, w2, ws, wsb);
    hipLaunchKernelGGL(main_kernel, dim3((N * K) / ROWS), dim3(256), 0, stream,
                       pair, pos, neigh, mask, ln_s, ln_b, b1, b2, ws, wsb, out);
}